// Round 17
// baseline (551.908 us; speedup 1.0000x reference)
//
#include <hip/hip_runtime.h>

#define NN 50000
#define EE 800000
#define HD 256
#define NSEG (2 * NN)
#define CHUNK 2048
#define NB ((NSEG + CHUNK - 1) / CHUNK)

typedef unsigned short u16;
typedef unsigned long long u64;
typedef short bf16x8 __attribute__((ext_vector_type(8)));
typedef float f32x4 __attribute__((ext_vector_type(4)));

__device__ __forceinline__ u16 f2bf_rne(float f) {
    unsigned u = __float_as_uint(f);
    return (u16)((u + 0x7FFF + ((u >> 16) & 1)) >> 16);
}
// trunc hi + RNE residual
__device__ __forceinline__ void split_tr(float v, u16& h, u16& l) {
    unsigned u = __float_as_uint(v);
    h = (u16)(u >> 16);
    l = f2bf_rne(v - __uint_as_float(u & 0xFFFF0000u));
}

// bijective XCD-chunked swizzle (m204)
__device__ __forceinline__ int xcd_swizzle(int orig, int nwg) {
    int q = nwg >> 3, r = nwg & 7;
    int xcd = orig & 7, idx = orig >> 3;
    return (xcd < r ? xcd * (q + 1) : r * (q + 1) + (xcd - r) * q) + idx;
}

// async global->LDS, 16B per lane
__device__ __forceinline__ void g2l16(const void* g, void* l) {
    __builtin_amdgcn_global_load_lds(
        (const __attribute__((address_space(1))) void*)g,
        (__attribute__((address_space(3))) void*)l, 16, 0, 0);
}

// bank swizzle for 64B-row bf16 tiles
__device__ __forceinline__ int swz2(int row) { return (row & 2) | ((row >> 2) & 1); }

// stage one 128x32 bf16 tile from G[rc][K] (k-contiguous), source-swizzled
__device__ __forceinline__ void stage_bf16(const u16* __restrict__ G, u16* S,
                                           int base_rc, int maxrc, int K, int k0, int tid) {
#pragma unroll
    for (int s = 0; s < 2; s++) {
        int slot = tid + s * 256;
        int row = slot >> 2, gg = slot & 3;
        int gsrc = gg ^ swz2(row);
        int arow = base_rc + row; arow = arow < maxrc ? arow : maxrc - 1;
        g2l16(G + (size_t)arow * K + k0 + gsrc * 8, S + ((tid & ~63) + s * 256) * 8);
    }
}

// ============ counted-vmcnt dbuf bf16 GEMM, single-pass: A bf16 [M][256], B bf16 ====
// acc = A*B. BM=BN=128, 4 waves 2x2, MFMA 16x16x32, k-map k=k0+g*8+j.
// MODE 1: lrelu -> bf16 out (w_in). MODE 2: relu; col<512 -> bf16 hrel; else f32 O2.
template<int MODE>
__global__ __launch_bounds__(256) void gemm_bf16s(
    const u16* __restrict__ Ag, const u16* __restrict__ Bg,
    const float* __restrict__ bias,
    u16* __restrict__ O1, float* __restrict__ O2,
    int M, int nxb)
{
    __shared__ __align__(16) u16 sA[2][128 * 32];
    __shared__ __align__(16) u16 sB[2][128 * 32];
    const int wgid = xcd_swizzle(blockIdx.x, gridDim.x);
    const int brow = (wgid / nxb) * 128, bcol = (wgid % nxb) * 128;
    const int tid = threadIdx.x, lane = tid & 63, w = tid >> 6;
    const int wr = w >> 1, wc = w & 1;
    const int r15 = lane & 15, g = lane >> 4;
    const int fsw = (g ^ swz2(r15)) * 8;

    f32x4 acc[4][4];
#pragma unroll
    for (int mi = 0; mi < 4; mi++)
#pragma unroll
        for (int ni = 0; ni < 4; ni++) acc[mi][ni] = (f32x4){0.f, 0.f, 0.f, 0.f};

    auto stage_step = [&](int k0, int b) {       // 4 VMEM instr per thread
        stage_bf16(Ag, sA[b], brow, M, 256, k0, tid);
        stage_bf16(Bg, sB[b], bcol, 1 << 30, 256, k0, tid);
    };
    auto compute_step = [&](int b) {
        bf16x8 af[4], bf[4];
#pragma unroll
        for (int mi = 0; mi < 4; mi++) {
            int idx = (wr * 64 + mi * 16 + r15) * 32 + fsw;
            af[mi] = *(const bf16x8*)&sA[b][idx];
        }
#pragma unroll
        for (int ni = 0; ni < 4; ni++) {
            int idx = (wc * 64 + ni * 16 + r15) * 32 + fsw;
            bf[ni] = *(const bf16x8*)&sB[b][idx];
        }
#pragma unroll
        for (int mi = 0; mi < 4; mi++)
#pragma unroll
            for (int ni = 0; ni < 4; ni++)
                acc[mi][ni] = __builtin_amdgcn_mfma_f32_16x16x32_bf16(af[mi], bf[ni], acc[mi][ni], 0, 0, 0);
    };

    stage_step(0, 0);
    stage_step(32, 1);
#pragma unroll
    for (int t = 0; t < 7; t++) {
        asm volatile("s_waitcnt vmcnt(4)" ::: "memory");   // drain buf[t&1] only
        __builtin_amdgcn_s_barrier();
        compute_step(t & 1);
        __builtin_amdgcn_s_barrier();
        if (t + 2 < 8) stage_step((t + 2) * 32, t & 1);
    }
    asm volatile("s_waitcnt vmcnt(0)" ::: "memory");
    __builtin_amdgcn_s_barrier();
    compute_step(1);

#pragma unroll
    for (int mi = 0; mi < 4; mi++) {
#pragma unroll
        for (int ni = 0; ni < 4; ni++) {
            int col = bcol + wc * 64 + ni * 16 + r15;
            float bsv = bias[col & (HD - 1)];
            int rbase = brow + wr * 64 + mi * 16 + g * 4;
#pragma unroll
            for (int r = 0; r < 4; r++) {
                int grow = rbase + r;
                if (grow >= M) continue;
                float v = acc[mi][ni][r] + bsv;
                if (MODE == 1) {
                    v = v > 0.f ? v : 0.01f * v;   // lrelu
                    O1[(size_t)grow * HD + col] = f2bf_rne(v);
                } else {
                    v = fmaxf(v, 0.f);             // relu
                    if (col < 2 * HD) {
                        O1[((size_t)(col >> 8) * NN + grow) * HD + (col & (HD - 1))] = f2bf_rne(v);
                    } else {
                        O2[(size_t)grow * HD + (col & (HD - 1))] = v;
                    }
                }
            }
        }
    }
}

// ===================== wave-autonomous dual-projection GEMM (K=768) =====================
// 128-thread blocks = 2 independent waves (no barriers). Each wave: 16 rows x 64 cols.
// 5-DEEP register prefetch of A (covers ~1000cy HBM latency); B 2-deep (L2-hot,
// fragment-major coalesced 1KB loads). A converted f32->hi/lo via perm, through
// wave-private LDS (dbuf, pad 40). Internal hi/lo MFMA; output bf16 hi only.
__global__ __launch_bounds__(128) void gemm_projW(
    const float* __restrict__ A0, const float* __restrict__ A1,
    const u16* __restrict__ B0, const u16* __restrict__ B1,
    const float* __restrict__ bias0, const float* __restrict__ bias1,
    u16* __restrict__ Ch)
{
    __shared__ __align__(16) u16 lds[2 * 2 * 2 * 640];   // [wave][buf][h/l][16*40]
    const int p = blockIdx.x & 1;
    const float* __restrict__ A = p ? A1 : A0;
    const u16* __restrict__ Bp = p ? B1 : B0;
    const float* __restrict__ bias = p ? bias1 : bias0;
    const int coff = p * 64;
    const int lane = threadIdx.x & 63, w = threadIdx.x >> 6;
    const int wrow = (blockIdx.x >> 1) * 32 + w * 16;
    const int r15 = lane & 15, g = lane >> 4;
    const int lbase = w * 2560;      // u16 units

    size_t aoff[2];
#pragma unroll
    for (int i = 0; i < 2; i++) {
        int row = wrow + (lane >> 3) + 8 * i;
        row = row < NN ? row : NN - 1;
        aoff[i] = (size_t)row * 768 + (lane & 7) * 4;
    }
    size_t boff[4];
#pragma unroll
    for (int ni = 0; ni < 4; ni++)
        boff[ni] = (size_t)(ni * 64 + lane) * 8;

    f32x4 acc[4];
#pragma unroll
    for (int ni = 0; ni < 4; ni++) acc[ni] = (f32x4){0.f, 0.f, 0.f, 0.f};

    float4 Ar[5][2];          // 5-slot A register ring
    uint4 Bs[2][4];           // 2-slot B ring

    auto loadA = [&](int t, float4 (&d)[2]) {
#pragma unroll
        for (int i = 0; i < 2; i++) d[i] = *(const float4*)&A[aoff[i] + t * 32];
    };
    auto loadB = [&](int t, uint4 (&d)[4]) {
#pragma unroll
        for (int ni = 0; ni < 4; ni++) d[ni] = *(const uint4*)&Bp[boff[ni] + (size_t)t * 2048];
    };
    auto writeA = [&](const float4 (&s)[2], int buf) {
#pragma unroll
        for (int i = 0; i < 2; i++) {
            int row2 = (lane >> 3) + 8 * i;
            unsigned e0 = __float_as_uint(s[i].x), e1 = __float_as_uint(s[i].y),
                     e2 = __float_as_uint(s[i].z), e3 = __float_as_uint(s[i].w);
            unsigned h0 = __builtin_amdgcn_perm(e1, e0, 0x07060302u);
            unsigned h1 = __builtin_amdgcn_perm(e3, e2, 0x07060302u);
            unsigned q0 = __float_as_uint(s[i].x - __uint_as_float(e0 & 0xFFFF0000u));
            unsigned q1 = __float_as_uint(s[i].y - __uint_as_float(e1 & 0xFFFF0000u));
            unsigned q2 = __float_as_uint(s[i].z - __uint_as_float(e2 & 0xFFFF0000u));
            unsigned q3 = __float_as_uint(s[i].w - __uint_as_float(e3 & 0xFFFF0000u));
            unsigned l0 = __builtin_amdgcn_perm(q1, q0, 0x07060302u);
            unsigned l1 = __builtin_amdgcn_perm(q3, q2, 0x07060302u);
            int idx = lbase + buf * 1280 + row2 * 40 + (lane & 7) * 4;
            *(u64*)&lds[idx] = (u64)h0 | ((u64)h1 << 32);
            *(u64*)&lds[idx + 640] = (u64)l0 | ((u64)l1 << 32);
        }
    };
    auto compute = [&](int buf, const uint4 (&Bv)[4]) {
        bf16x8 afh, afl;
        {
            int idx = lbase + buf * 1280 + r15 * 40 + g * 8;
            afh = *(const bf16x8*)&lds[idx];
            afl = *(const bf16x8*)&lds[idx + 640];
        }
#pragma unroll
        for (int ni = 0; ni < 4; ni++) {
            bf16x8 bb = __builtin_bit_cast(bf16x8, Bv[ni]);
            acc[ni] = __builtin_amdgcn_mfma_f32_16x16x32_bf16(afh, bb, acc[ni], 0, 0, 0);
            acc[ni] = __builtin_amdgcn_mfma_f32_16x16x32_bf16(afl, bb, acc[ni], 0, 0, 0);
        }
    };

    // prologue (NT = 24): A tiles 0..4 in flight, B tiles 0..1
#pragma unroll
    for (int i = 0; i < 5; i++) loadA(i, Ar[i]);
    loadB(0, Bs[0]);
    loadB(1, Bs[1]);
    writeA(Ar[0], 0);
    // fully unrolled steady+tail: all ring indices compile-time
#pragma unroll
    for (int t = 0; t < 24; t++) {
        compute(t & 1, Bs[t & 1]);
        if (t + 5 < 24) loadA(t + 5, Ar[(t + 5) % 5]);
        if (t + 2 < 24) loadB(t + 2, Bs[t & 1]);
        if (t + 1 < 24) writeA(Ar[(t + 1) % 5], (t + 1) & 1);
    }

    // ---- coalesced epilogue: acc -> wave-private LDS (h plane) -> 16B stores ----
    u16* tlh = &lds[lbase];          // 16 x 72 u16 (pad 8)
#pragma unroll
    for (int ni = 0; ni < 4; ni++) {
        int col = ni * 16 + r15;
        float bsv = bias[col];
#pragma unroll
        for (int r = 0; r < 4; r++) {
            int row = g * 4 + r;
            float v = acc[ni][r] + bsv;
            v = v > 0.f ? v : 0.01f * v;   // lrelu
            tlh[row * 72 + col] = f2bf_rne(v);
        }
    }
    asm volatile("s_waitcnt lgkmcnt(0)" ::: "memory");
    __builtin_amdgcn_sched_barrier(0);
    {
        int row = lane >> 2, cb = (lane & 3) * 16;
        int grow = wrow + row;
        if (grow < NN) {
#pragma unroll
            for (int j = 0; j < 2; j++) {
                uint4 hv = *(const uint4*)&tlh[row * 72 + cb + j * 8];
                *(uint4*)&Ch[(size_t)grow * HD + coff + cb + j * 8] = hv;
            }
        }
    }
}

// ---- weight RNE-round+transpose: W f32 [K][Ncol] -> T bf16 [colOff+n][K] ----
__global__ void conv_w(const float* __restrict__ W, int K, int Ncol,
                       u16* __restrict__ Th, int colOff)
{
    int i = blockIdx.x * 256 + threadIdx.x;
    if (i >= K * Ncol) return;
    int k = i / Ncol, n = i % Ncol;
    Th[(size_t)(colOff + n) * K + k] = f2bf_rne(W[i]);
}

// ---- projection weights -> fragment-major: Bf[((t*4+ni)*64+lane)*8+j], K=768, Ncol=64 ----
__global__ void conv_wf(const float* __restrict__ W, u16* __restrict__ Bf)
{
    int i = blockIdx.x * 256 + threadIdx.x;
    if (i >= 768 * 64) return;
    int k = i >> 6, n = i & 63;
    int t = k >> 5, kk = k & 31, g = kk >> 3, j = kk & 7;
    int lane = g * 16 + (n & 15), ni = n >> 4;
    Bf[(size_t)((t * 4 + ni) * 64 + lane) * 8 + j] = f2bf_rne(W[i]);
}

// ---------------- small f32 GEMM (K=5/3), bf16 out ----------------
template<int BM, int BN, int BK, int TM, int TN>
__global__ __launch_bounds__(256) void gemm_f32s(
    const float* __restrict__ A, int lda,
    const float* __restrict__ B, int ldb,
    const float* __restrict__ bias,
    u16* __restrict__ Ch, int coff,
    int M, int Ncol, int K)
{
    constexpr int TX = BN / TN;
    __shared__ float As[BK][BM + 4];
    __shared__ float Bs[BK][BN + 4];
    const int tid = threadIdx.x;
    const int tx = tid % TX, ty = tid / TX;
    const int brow = blockIdx.y * BM;
    const int bcol = blockIdx.x * BN;
    float acc[TM][TN];
#pragma unroll
    for (int i = 0; i < TM; i++)
#pragma unroll
        for (int j = 0; j < TN; j++) acc[i][j] = 0.f;
    for (int k0 = 0; k0 < K; k0 += BK) {
#pragma unroll
        for (int idx = tid; idx < BM * BK; idx += 256) {
            int m = idx / BK, k = idx % BK;
            int gr = brow + m, gk = k0 + k;
            As[k][m] = (gr < M && gk < K) ? A[(size_t)gr * lda + gk] : 0.f;
        }
#pragma unroll
        for (int idx = tid; idx < BK * BN; idx += 256) {
            int k = idx / BN, n = idx % BN;
            int gk = k0 + k, gc = bcol + n;
            Bs[k][n] = (gk < K && gc < Ncol) ? B[(size_t)gk * ldb + gc] : 0.f;
        }
        __syncthreads();
#pragma unroll
        for (int k = 0; k < BK; k++) {
            float a[TM], b[TN];
#pragma unroll
            for (int i = 0; i < TM; i++) a[i] = As[k][ty * TM + i];
#pragma unroll
            for (int j = 0; j < TN; j++) b[j] = Bs[k][tx * TN + j];
#pragma unroll
            for (int i = 0; i < TM; i++)
#pragma unroll
                for (int j = 0; j < TN; j++) acc[i][j] = fmaf(a[i], b[j], acc[i][j]);
        }
        __syncthreads();
    }
#pragma unroll
    for (int i = 0; i < TM; i++) {
        int gr = brow + ty * TM + i;
        if (gr >= M) continue;
#pragma unroll
        for (int j = 0; j < TN; j++) {
            int gc = bcol + tx * TN + j;
            if (gc >= Ncol) continue;
            float v = acc[i][j] + bias[gc];
            v = v > 0.f ? v : 0.01f * v;
            Ch[(size_t)gr * HD + coff + gc] = f2bf_rne(v);
        }
    }
}

// ---------------- CSR build ----------------
__global__ void count_seg(const int* __restrict__ ei, const int* __restrict__ et,
                          int* __restrict__ segc)
{
    int e = blockIdx.x * blockDim.x + threadIdx.x;
    if (e < EE) {
        int dst = ei[EE + e];
        int r = et[e];
        atomicAdd(&segc[r * NN + dst], 1);
    }
}

__global__ __launch_bounds__(256) void scan_local(const int* __restrict__ segc,
                                                  int* __restrict__ offs,
                                                  int* __restrict__ bsum)
{
    int b = blockIdx.x;
    int base = b * CHUNK;
    int tid = threadIdx.x;
    int lane = tid & 63, wave = tid >> 6;
    __shared__ int wsum[4];
    int vals[8];
    int i0 = base + tid * 8;
    int s = 0;
    if (i0 + 7 < NSEG) {
        int4 v0 = *(const int4*)&segc[i0];
        int4 v1 = *(const int4*)&segc[i0 + 4];
        vals[0] = v0.x; vals[1] = v0.y; vals[2] = v0.z; vals[3] = v0.w;
        vals[4] = v1.x; vals[5] = v1.y; vals[6] = v1.z; vals[7] = v1.w;
    } else {
#pragma unroll
        for (int j = 0; j < 8; j++) vals[j] = (i0 + j < NSEG) ? segc[i0 + j] : 0;
    }
#pragma unroll
    for (int j = 0; j < 8; j++) s += vals[j];
    int v = s;
#pragma unroll
    for (int off = 1; off < 64; off <<= 1) {
        int u = __shfl_up(v, off);
        if (lane >= off) v += u;
    }
    if (lane == 63) wsum[wave] = v;
    __syncthreads();
    int wbase = 0;
#pragma unroll
    for (int ww = 0; ww < 4; ww++) if (ww < wave) wbase += wsum[ww];
    int run = wbase + v - s;
#pragma unroll
    for (int j = 0; j < 8; j++) {
        run += vals[j];
        int i = i0 + j;
        if (i < NSEG) offs[i + 1] = run;
    }
    if (tid == 0) {
        int t = 0;
#pragma unroll
        for (int ww = 0; ww < 4; ww++) t += wsum[ww];
        bsum[b] = t;
    }
}

__global__ void scan_bsum(const int* __restrict__ bsum, int* __restrict__ bbase)
{
    int lane = threadIdx.x;
    int c = (lane < NB) ? bsum[lane] : 0;
    int v = c;
#pragma unroll
    for (int off = 1; off < 64; off <<= 1) {
        int u = __shfl_up(v, off);
        if (lane >= off) v += u;
    }
    if (lane < NB) bbase[lane] = v - c;
}

__global__ void add_base(int* __restrict__ offs, const int* __restrict__ bbase)
{
    int i = blockIdx.x * blockDim.x + threadIdx.x;
    if (i < NSEG) offs[i + 1] += bbase[i / CHUNK];
    if (i == 0) offs[0] = 0;
}

__global__ void fill_src(const int* __restrict__ ei, const int* __restrict__ et,
                         const int* __restrict__ offs, int* __restrict__ cursor,
                         int* __restrict__ src_list)
{
    int e = blockIdx.x * blockDim.x + threadIdx.x;
    if (e < EE) {
        int src = ei[e];
        int dst = ei[EE + e];
        int s = et[e] * NN + dst;
        int pos = offs[s] + atomicAdd(&cursor[s], 1);
        src_list[pos] = src;
    }
}

// ---------------- gather: v = base + sum_r mean(hrel_bf16) ----------------
// OUTM 0: write bf16 (next layer input).  OUTM 1: fused head -> logits.
template<int OUTM>
__global__ __launch_bounds__(256) void gather_mean_b(
    const u16* __restrict__ hrelb,
    const int* __restrict__ offs,
    const int* __restrict__ src_list,
    const float* __restrict__ basein,
    u16* __restrict__ Oh,
    const float* __restrict__ wout, const float* __restrict__ bout,
    float* __restrict__ logits)
{
    int d = blockIdx.x * 4 + (threadIdx.x >> 6);
    if (d >= NN) return;
    int lane = threadIdx.x & 63;
    f32x4 acc = {0.f, 0.f, 0.f, 0.f};
#pragma unroll
    for (int r = 0; r < 2; r++) {
        int s = r * NN + d;
        int start = offs[s], end = offs[s + 1];
        if (start == end) continue;
        f32x4 a = {0.f, 0.f, 0.f, 0.f};
        const u16* hb = hrelb + (size_t)r * NN * HD;
        for (int i = start; i < end; i++) {
            int src = src_list[i];
            uint2 wv = *(const uint2*)(hb + (size_t)src * HD + lane * 4);
            a.x += __uint_as_float(wv.x << 16);
            a.y += __uint_as_float(wv.x & 0xFFFF0000u);
            a.z += __uint_as_float(wv.y << 16);
            a.w += __uint_as_float(wv.y & 0xFFFF0000u);
        }
        float inv = 1.0f / (float)(end - start);
        acc.x += a.x * inv; acc.y += a.y * inv;
        acc.z += a.z * inv; acc.w += a.w * inv;
    }
    float4 b = ((const float4*)(basein + (size_t)d * HD))[lane];
    float v0 = b.x + acc.x, v1 = b.y + acc.y, v2 = b.z + acc.z, v3 = b.w + acc.w;
    if (OUTM == 0) {
        uint2 uh;
        uh.x = (unsigned)f2bf_rne(v0) | ((unsigned)f2bf_rne(v1) << 16);
        uh.y = (unsigned)f2bf_rne(v2) | ((unsigned)f2bf_rne(v3) << 16);
        *(uint2*)(Oh + (size_t)d * HD + lane * 4) = uh;
    } else {
        int k = lane * 4;
        float a0 = v0 * wout[(k + 0) * 2 + 0] + v1 * wout[(k + 1) * 2 + 0]
                 + v2 * wout[(k + 2) * 2 + 0] + v3 * wout[(k + 3) * 2 + 0];
        float a1 = v0 * wout[(k + 0) * 2 + 1] + v1 * wout[(k + 1) * 2 + 1]
                 + v2 * wout[(k + 2) * 2 + 1] + v3 * wout[(k + 3) * 2 + 1];
#pragma unroll
        for (int off = 32; off > 0; off >>= 1) {
            a0 += __shfl_down(a0, off);
            a1 += __shfl_down(a1, off);
        }
        if (lane == 0) {
            logits[(size_t)d * 2 + 0] = a0 + bout[0];
            logits[(size_t)d * 2 + 1] = a1 + bout[1];
        }
    }
}

extern "C" void kernel_launch(void* const* d_in, const int* in_sizes, int n_in,
                              void* d_out, int out_size, void* d_ws, size_t ws_size,
                              hipStream_t stream)
{
    const float* des   = (const float*)d_in[0];
    const float* tweet = (const float*)d_in[1];
    const float* nump  = (const float*)d_in[2];
    const float* catp  = (const float*)d_in[3];
    const int*   ei    = (const int*)d_in[4];
    const int*   et    = (const int*)d_in[5];
    const float* w_des = (const float*)d_in[6],  *b_des = (const float*)d_in[7];
    const float* w_tw  = (const float*)d_in[8],  *b_tw  = (const float*)d_in[9];
    const float* w_num = (const float*)d_in[10], *b_num = (const float*)d_in[11];
    const float* w_cat = (const float*)d_in[12], *b_cat = (const float*)d_in[13];
    const float* w_in  = (const float*)d_in[14], *b_in  = (const float*)d_in[15];
    const float* weight1 = (const float*)d_in[16], *root1 = (const float*)d_in[17], *bias1 = (const float*)d_in[18];
    const float* weight2 = (const float*)d_in[19], *root2 = (const float*)d_in[20], *bias2 = (const float*)d_in[21];
    const float* w_out = (const float*)d_in[22], *b_out = (const float*)d_in[23];
    float* outp = (float*)d_out;

    const int HSZ = HD * HD, PSZ = 768 * 64;

    // ---- workspace carve-up ----
    float* base  = (float*)d_ws;                       // [N,HD] f32
    u16*   hrelb = (u16*)(base + (size_t)NN * HD);     // [2,N,HD] bf16
    u16*   xh    = hrelb + (size_t)2 * NN * HD;        // [N,HD] bf16
    u16*   yh    = xh + (size_t)NN * HD;               // [N,HD] bf16
    int*   offs  = (int*)(yh + (size_t)NN * HD);
    int*   segc  = offs + (NSEG + 1);
    int*   srcl  = segc + NSEG;
    int*   bsum  = srcl + EE;
    int*   bbase = bsum + NB;
    uintptr_t wp = ((uintptr_t)(bbase + NB) + 15) & ~(uintptr_t)15;
    u16* desB = (u16*)wp;
    u16* twB  = desB + PSZ;
    u16* winB = twB + PSZ;
    u16* cat1 = winB + HSZ;
    u16* cat2 = cat1 + 3 * HSZ;

    // ---- CSR build ----
    hipMemsetAsync(segc, 0, NSEG * sizeof(int), stream);
    count_seg<<<(EE + 255) / 256, 256, 0, stream>>>(ei, et, segc);
    scan_local<<<NB, 256, 0, stream>>>(segc, offs, bsum);
    scan_bsum<<<1, 64, 0, stream>>>(bsum, bbase);
    add_base<<<(NSEG + 255) / 256, 256, 0, stream>>>(offs, bbase);
    hipMemsetAsync(segc, 0, NSEG * sizeof(int), stream);
    fill_src<<<(EE + 255) / 256, 256, 0, stream>>>(ei, et, offs, segc, srcl);

    // ---- weight conversion ----
    conv_wf<<<(PSZ + 255) / 256, 256, 0, stream>>>(w_des, desB);   // fragment-major
    conv_wf<<<(PSZ + 255) / 256, 256, 0, stream>>>(w_tw,  twB);    // fragment-major
    conv_w<<<(HSZ + 255) / 256, 256, 0, stream>>>(w_in, HD, HD, winB, 0);
    conv_w<<<(HSZ + 255) / 256, 256, 0, stream>>>(weight1,       HD, HD, cat1, 0);
    conv_w<<<(HSZ + 255) / 256, 256, 0, stream>>>(weight1 + HSZ, HD, HD, cat1, 256);
    conv_w<<<(HSZ + 255) / 256, 256, 0, stream>>>(root1,         HD, HD, cat1, 512);
    conv_w<<<(HSZ + 255) / 256, 256, 0, stream>>>(weight2,       HD, HD, cat2, 0);
    conv_w<<<(HSZ + 255) / 256, 256, 0, stream>>>(weight2 + HSZ, HD, HD, cat2, 256);
    conv_w<<<(HSZ + 255) / 256, 256, 0, stream>>>(root2,         HD, HD, cat2, 512);

    const int NYB = (NN + 127) / 128;    // 391 (128-row blocks)
    const int NWB = (NN + 31) / 32;      // 1563 (32-row blocks = 2 waves x 16 rows)

    // ---- fused feature projections (des+tweet) -> xh ----
    gemm_projW<<<2 * NWB, 128, 0, stream>>>(des, tweet, desB, twB, b_des, b_tw, xh);
    dim3 gsmall(1, (NN + 63) / 64);
    gemm_f32s<64, 64, 8, 4, 4><<<gsmall, 256, 0, stream>>>(nump, 5, w_num, 64, b_num, xh, 128, NN, 64, 5);
    gemm_f32s<64, 64, 8, 4, 4><<<gsmall, 256, 0, stream>>>(catp, 3, w_cat, 64, b_cat, xh, 192, NN, 64, 3);

    // ---- y = lrelu(x @ w_in + b_in) -> yh ----
    gemm_bf16s<1><<<2 * NYB, 256, 0, stream>>>(xh, winB, b_in, yh, nullptr, NN, 2);

    // ---- layer 1: fused [W_r0|W_r1|root1] -> hrelb (bf16) + base (f32) ----
    gemm_bf16s<2><<<6 * NYB, 256, 0, stream>>>(yh, cat1, bias1, hrelb, base, NN, 6);
    gather_mean_b<0><<<(NN + 3) / 4, 256, 0, stream>>>(hrelb, offs, srcl, base, xh, nullptr, nullptr, nullptr);

    // ---- layer 2 + fused output head ----
    gemm_bf16s<2><<<6 * NYB, 256, 0, stream>>>(xh, cat2, bias2, hrelb, base, NN, 6);
    gather_mean_b<1><<<(NN + 3) / 4, 256, 0, stream>>>(hrelb, offs, srcl, base, nullptr, w_out, b_out, outp);
}

// Round 18
// 529.616 us; speedup vs baseline: 1.0421x; 1.0421x over previous
//
#include <hip/hip_runtime.h>

#define NN 50000
#define EE 800000
#define HD 256
#define NSEG (2 * NN)
#define CHUNK 2048
#define NB ((NSEG + CHUNK - 1) / CHUNK)

typedef unsigned short u16;
typedef unsigned long long u64;
typedef short bf16x8 __attribute__((ext_vector_type(8)));
typedef float f32x4 __attribute__((ext_vector_type(4)));

__device__ __forceinline__ u16 f2bf_rne(float f) {
    unsigned u = __float_as_uint(f);
    return (u16)((u + 0x7FFF + ((u >> 16) & 1)) >> 16);
}
// trunc hi + RNE residual
__device__ __forceinline__ void split_tr(float v, u16& h, u16& l) {
    unsigned u = __float_as_uint(v);
    h = (u16)(u >> 16);
    l = f2bf_rne(v - __uint_as_float(u & 0xFFFF0000u));
}

// bijective XCD-chunked swizzle (m204)
__device__ __forceinline__ int xcd_swizzle(int orig, int nwg) {
    int q = nwg >> 3, r = nwg & 7;
    int xcd = orig & 7, idx = orig >> 3;
    return (xcd < r ? xcd * (q + 1) : r * (q + 1) + (xcd - r) * q) + idx;
}

// async global->LDS, 16B per lane
__device__ __forceinline__ void g2l16(const void* g, void* l) {
    __builtin_amdgcn_global_load_lds(
        (const __attribute__((address_space(1))) void*)g,
        (__attribute__((address_space(3))) void*)l, 16, 0, 0);
}

// bank swizzle for 64B-row bf16 tiles
__device__ __forceinline__ int swz2(int row) { return (row & 2) | ((row >> 2) & 1); }

// stage one 128x32 bf16 tile from G[rc][K] (k-contiguous), source-swizzled
__device__ __forceinline__ void stage_bf16(const u16* __restrict__ G, u16* S,
                                           int base_rc, int maxrc, int K, int k0, int tid) {
#pragma unroll
    for (int s = 0; s < 2; s++) {
        int slot = tid + s * 256;
        int row = slot >> 2, gg = slot & 3;
        int gsrc = gg ^ swz2(row);
        int arow = base_rc + row; arow = arow < maxrc ? arow : maxrc - 1;
        g2l16(G + (size_t)arow * K + k0 + gsrc * 8, S + ((tid & ~63) + s * 256) * 8);
    }
}

// ============ counted-vmcnt dbuf bf16 GEMM, single-pass: A bf16 [M][256], B bf16 ====
// acc = A*B. BM=BN=128, 4 waves 2x2, MFMA 16x16x32, k-map k=k0+g*8+j.
// MODE 1: lrelu -> bf16 out (w_in). MODE 2: relu; col<512 -> bf16 hrel; else f32 O2.
template<int MODE>
__global__ __launch_bounds__(256) void gemm_bf16s(
    const u16* __restrict__ Ag, const u16* __restrict__ Bg,
    const float* __restrict__ bias,
    u16* __restrict__ O1, float* __restrict__ O2,
    int M, int nxb)
{
    __shared__ __align__(16) u16 sA[2][128 * 32];
    __shared__ __align__(16) u16 sB[2][128 * 32];
    const int wgid = xcd_swizzle(blockIdx.x, gridDim.x);
    const int brow = (wgid / nxb) * 128, bcol = (wgid % nxb) * 128;
    const int tid = threadIdx.x, lane = tid & 63, w = tid >> 6;
    const int wr = w >> 1, wc = w & 1;
    const int r15 = lane & 15, g = lane >> 4;
    const int fsw = (g ^ swz2(r15)) * 8;

    f32x4 acc[4][4];
#pragma unroll
    for (int mi = 0; mi < 4; mi++)
#pragma unroll
        for (int ni = 0; ni < 4; ni++) acc[mi][ni] = (f32x4){0.f, 0.f, 0.f, 0.f};

    auto stage_step = [&](int k0, int b) {       // 4 VMEM instr per thread
        stage_bf16(Ag, sA[b], brow, M, 256, k0, tid);
        stage_bf16(Bg, sB[b], bcol, 1 << 30, 256, k0, tid);
    };
    auto compute_step = [&](int b) {
        bf16x8 af[4], bf[4];
#pragma unroll
        for (int mi = 0; mi < 4; mi++) {
            int idx = (wr * 64 + mi * 16 + r15) * 32 + fsw;
            af[mi] = *(const bf16x8*)&sA[b][idx];
        }
#pragma unroll
        for (int ni = 0; ni < 4; ni++) {
            int idx = (wc * 64 + ni * 16 + r15) * 32 + fsw;
            bf[ni] = *(const bf16x8*)&sB[b][idx];
        }
#pragma unroll
        for (int mi = 0; mi < 4; mi++)
#pragma unroll
            for (int ni = 0; ni < 4; ni++)
                acc[mi][ni] = __builtin_amdgcn_mfma_f32_16x16x32_bf16(af[mi], bf[ni], acc[mi][ni], 0, 0, 0);
    };

    stage_step(0, 0);
    stage_step(32, 1);
#pragma unroll
    for (int t = 0; t < 7; t++) {
        asm volatile("s_waitcnt vmcnt(4)" ::: "memory");   // drain buf[t&1] only
        __builtin_amdgcn_s_barrier();
        compute_step(t & 1);
        __builtin_amdgcn_s_barrier();
        if (t + 2 < 8) stage_step((t + 2) * 32, t & 1);
    }
    asm volatile("s_waitcnt vmcnt(0)" ::: "memory");
    __builtin_amdgcn_s_barrier();
    compute_step(1);

#pragma unroll
    for (int mi = 0; mi < 4; mi++) {
#pragma unroll
        for (int ni = 0; ni < 4; ni++) {
            int col = bcol + wc * 64 + ni * 16 + r15;
            float bsv = bias[col & (HD - 1)];
            int rbase = brow + wr * 64 + mi * 16 + g * 4;
#pragma unroll
            for (int r = 0; r < 4; r++) {
                int grow = rbase + r;
                if (grow >= M) continue;
                float v = acc[mi][ni][r] + bsv;
                if (MODE == 1) {
                    v = v > 0.f ? v : 0.01f * v;   // lrelu
                    O1[(size_t)grow * HD + col] = f2bf_rne(v);
                } else {
                    v = fmaxf(v, 0.f);             // relu
                    if (col < 2 * HD) {
                        O1[((size_t)(col >> 8) * NN + grow) * HD + (col & (HD - 1))] = f2bf_rne(v);
                    } else {
                        O2[(size_t)grow * HD + (col & (HD - 1))] = v;
                    }
                }
            }
        }
    }
}

// ===================== wave-autonomous dual-projection GEMM (K=768) =====================
// Round-16 proven version (123us plateau). 128-thread blocks = 2 independent waves.
// Each wave: 16 rows x 64 cols; A f32 coalesced->regs->perm-convert(hi/lo)->private LDS
// (dbuf, pad 40); B fragment-major coalesced. Internal hi/lo MFMA; output bf16 hi only.
__global__ __launch_bounds__(128) void gemm_projW(
    const float* __restrict__ A0, const float* __restrict__ A1,
    const u16* __restrict__ B0, const u16* __restrict__ B1,
    const float* __restrict__ bias0, const float* __restrict__ bias1,
    u16* __restrict__ Ch)
{
    __shared__ __align__(16) u16 lds[2 * 2 * 2 * 640];   // [wave][buf][h/l][16*40]
    const int p = blockIdx.x & 1;
    const float* __restrict__ A = p ? A1 : A0;
    const u16* __restrict__ Bp = p ? B1 : B0;
    const float* __restrict__ bias = p ? bias1 : bias0;
    const int coff = p * 64;
    const int lane = threadIdx.x & 63, w = threadIdx.x >> 6;
    const int wrow = (blockIdx.x >> 1) * 32 + w * 16;
    const int r15 = lane & 15, g = lane >> 4;
    const int lbase = w * 2560;      // u16 units

    size_t aoff[2];
#pragma unroll
    for (int i = 0; i < 2; i++) {
        int row = wrow + (lane >> 3) + 8 * i;
        row = row < NN ? row : NN - 1;
        aoff[i] = (size_t)row * 768 + (lane & 7) * 4;
    }
    size_t boff[4];
#pragma unroll
    for (int ni = 0; ni < 4; ni++)
        boff[ni] = (size_t)(ni * 64 + lane) * 8;

    f32x4 acc[4];
#pragma unroll
    for (int ni = 0; ni < 4; ni++) acc[ni] = (f32x4){0.f, 0.f, 0.f, 0.f};

    float4 Ar0[2], Ar1[2];
    uint4 Bs0[4], Bs1[4];

    auto loadA = [&](int t, float4 (&d)[2]) {
#pragma unroll
        for (int i = 0; i < 2; i++) d[i] = *(const float4*)&A[aoff[i] + t * 32];
    };
    auto loadB = [&](int t, uint4 (&d)[4]) {
#pragma unroll
        for (int ni = 0; ni < 4; ni++) d[ni] = *(const uint4*)&Bp[boff[ni] + (size_t)t * 2048];
    };
    auto writeA = [&](const float4 (&s)[2], int buf) {
#pragma unroll
        for (int i = 0; i < 2; i++) {
            int row2 = (lane >> 3) + 8 * i;
            unsigned e0 = __float_as_uint(s[i].x), e1 = __float_as_uint(s[i].y),
                     e2 = __float_as_uint(s[i].z), e3 = __float_as_uint(s[i].w);
            unsigned h0 = __builtin_amdgcn_perm(e1, e0, 0x07060302u);
            unsigned h1 = __builtin_amdgcn_perm(e3, e2, 0x07060302u);
            unsigned q0 = __float_as_uint(s[i].x - __uint_as_float(e0 & 0xFFFF0000u));
            unsigned q1 = __float_as_uint(s[i].y - __uint_as_float(e1 & 0xFFFF0000u));
            unsigned q2 = __float_as_uint(s[i].z - __uint_as_float(e2 & 0xFFFF0000u));
            unsigned q3 = __float_as_uint(s[i].w - __uint_as_float(e3 & 0xFFFF0000u));
            unsigned l0 = __builtin_amdgcn_perm(q1, q0, 0x07060302u);
            unsigned l1 = __builtin_amdgcn_perm(q3, q2, 0x07060302u);
            int idx = lbase + buf * 1280 + row2 * 40 + (lane & 7) * 4;
            *(u64*)&lds[idx] = (u64)h0 | ((u64)h1 << 32);
            *(u64*)&lds[idx + 640] = (u64)l0 | ((u64)l1 << 32);
        }
    };
    auto compute = [&](int buf, const uint4 (&Bv)[4]) {
        bf16x8 afh, afl;
        {
            int idx = lbase + buf * 1280 + r15 * 40 + g * 8;
            afh = *(const bf16x8*)&lds[idx];
            afl = *(const bf16x8*)&lds[idx + 640];
        }
#pragma unroll
        for (int ni = 0; ni < 4; ni++) {
            bf16x8 bb = __builtin_bit_cast(bf16x8, Bv[ni]);
            acc[ni] = __builtin_amdgcn_mfma_f32_16x16x32_bf16(afh, bb, acc[ni], 0, 0, 0);
            acc[ni] = __builtin_amdgcn_mfma_f32_16x16x32_bf16(afl, bb, acc[ni], 0, 0, 0);
        }
    };

    // prologue (NT = 24)
    loadA(0, Ar0); loadB(0, Bs0);
    writeA(Ar0, 0);
    loadA(1, Ar1); loadB(1, Bs1);
    for (int tt = 0; tt < 11; ++tt) {
        int t0 = 2 * tt;
        loadA(t0 + 2, Ar0);
        compute(0, Bs0);
        loadB(t0 + 2, Bs0);
        writeA(Ar1, 1);
        loadA(t0 + 3, Ar1);
        compute(1, Bs1);
        loadB(t0 + 3, Bs1);
        writeA(Ar0, 0);
    }
    compute(0, Bs0);     // t=22
    writeA(Ar1, 1);      // tile 23 -> buf1
    compute(1, Bs1);     // t=23

    // ---- coalesced epilogue: acc -> wave-private LDS (h plane) -> 16B stores ----
    u16* tlh = &lds[lbase];          // 16 x 72 u16 (pad 8)
#pragma unroll
    for (int ni = 0; ni < 4; ni++) {
        int col = ni * 16 + r15;
        float bsv = bias[col];
#pragma unroll
        for (int r = 0; r < 4; r++) {
            int row = g * 4 + r;
            float v = acc[ni][r] + bsv;
            v = v > 0.f ? v : 0.01f * v;   // lrelu
            tlh[row * 72 + col] = f2bf_rne(v);
        }
    }
    asm volatile("s_waitcnt lgkmcnt(0)" ::: "memory");
    __builtin_amdgcn_sched_barrier(0);
    {
        int row = lane >> 2, cb = (lane & 3) * 16;
        int grow = wrow + row;
        if (grow < NN) {
#pragma unroll
            for (int j = 0; j < 2; j++) {
                uint4 hv = *(const uint4*)&tlh[row * 72 + cb + j * 8];
                *(uint4*)&Ch[(size_t)grow * HD + coff + cb + j * 8] = hv;
            }
        }
    }
}

// ==== batched weight conversion: all 9 weight tensors in ONE launch ====
// seg layout by global index:
//   [0, 49152)          : w_des  -> desB (fragment-major)
//   [49152, 98304)      : w_tw   -> twB  (fragment-major)
//   [98304, 98304+7*65536): 7 x 256x256 tensors -> bf16 [colOff+n][256]
//      seg 0: w_in -> winB(0); 1-3: weight1/weight1+HSZ/root1 -> cat1(0/256/512);
//      4-6: weight2/weight2+HSZ/root2 -> cat2(0/256/512)
__global__ void conv_all(
    const float* __restrict__ w_des, const float* __restrict__ w_tw,
    const float* __restrict__ w_in,
    const float* __restrict__ weight1, const float* __restrict__ root1,
    const float* __restrict__ weight2, const float* __restrict__ root2,
    u16* __restrict__ desB, u16* __restrict__ twB,
    u16* __restrict__ winB, u16* __restrict__ cat1, u16* __restrict__ cat2)
{
    const int HSZ = HD * HD;
    int idx = blockIdx.x * 256 + threadIdx.x;
    if (idx < 98304) {
        // fragment-major projection weights: K=768, Ncol=64
        const float* W = idx < 49152 ? w_des : w_tw;
        u16* Bf = idx < 49152 ? desB : twB;
        int i = idx < 49152 ? idx : idx - 49152;
        int k = i >> 6, n = i & 63;
        int t = k >> 5, kk = k & 31, g = kk >> 3, j = kk & 7;
        int lane = g * 16 + (n & 15), ni = n >> 4;
        Bf[(size_t)((t * 4 + ni) * 64 + lane) * 8 + j] = f2bf_rne(W[i]);
        return;
    }
    int jdx = idx - 98304;
    int seg = jdx >> 16;         // 0..6
    if (seg >= 7) return;
    int i = jdx & 65535;
    const float* srcs[7] = {w_in, weight1, weight1 + HSZ, root1,
                            weight2, weight2 + HSZ, root2};
    u16* dsts[7] = {winB, cat1, cat1 + 256 * 256, cat1 + 512 * 256,
                    cat2, cat2 + 256 * 256, cat2 + 512 * 256};
    int k = i >> 8, n = i & 255;
    dsts[seg][(size_t)n * 256 + k] = f2bf_rne(srcs[seg][i]);
}

// ---------------- merged small f32 GEMM (nump K=5 & catp K=3), bf16 out ----------------
// blockIdx.x selects input; BM=64, BN=64, BK=8, TM=TN=4.
__global__ __launch_bounds__(256) void gemm_f32s2(
    const float* __restrict__ A0, const float* __restrict__ A1,
    const float* __restrict__ B0, const float* __restrict__ B1,
    const float* __restrict__ bias0, const float* __restrict__ bias1,
    u16* __restrict__ Ch)
{
    const int p = blockIdx.x;
    const float* __restrict__ A = p ? A1 : A0;
    const float* __restrict__ B = p ? B1 : B0;
    const float* __restrict__ bias = p ? bias1 : bias0;
    const int lda = p ? 3 : 5, K = lda, coff = p ? 192 : 128;

    __shared__ float As[8][64 + 4];
    __shared__ float Bs[8][64 + 4];
    const int tid = threadIdx.x;
    const int tx = tid % 16, ty = tid / 16;
    const int brow = blockIdx.y * 64;
    float acc[4][4];
#pragma unroll
    for (int i = 0; i < 4; i++)
#pragma unroll
        for (int j = 0; j < 4; j++) acc[i][j] = 0.f;

    // single K-panel (K<=8)
#pragma unroll 2
    for (int idx = tid; idx < 64 * 8; idx += 256) {
        int m = idx / 8, k = idx % 8;
        int gr = brow + m;
        As[k][m] = (gr < NN && k < K) ? A[(size_t)gr * lda + k] : 0.f;
    }
#pragma unroll 2
    for (int idx = tid; idx < 8 * 64; idx += 256) {
        int k = idx / 64, n = idx % 64;
        Bs[k][n] = (k < K) ? B[(size_t)k * 64 + n] : 0.f;
    }
    __syncthreads();
#pragma unroll
    for (int k = 0; k < 8; k++) {
        float a[4], b[4];
#pragma unroll
        for (int i = 0; i < 4; i++) a[i] = As[k][ty * 4 + i];
#pragma unroll
        for (int j = 0; j < 4; j++) b[j] = Bs[k][tx * 4 + j];
#pragma unroll
        for (int i = 0; i < 4; i++)
#pragma unroll
            for (int j = 0; j < 4; j++) acc[i][j] = fmaf(a[i], b[j], acc[i][j]);
    }

#pragma unroll
    for (int i = 0; i < 4; i++) {
        int gr = brow + ty * 4 + i;
        if (gr >= NN) continue;
#pragma unroll
        for (int j = 0; j < 4; j++) {
            int gc = tx * 4 + j;
            float v = acc[i][j] + bias[gc];
            v = v > 0.f ? v : 0.01f * v;
            Ch[(size_t)gr * HD + coff + gc] = f2bf_rne(v);
        }
    }
}

// ---------------- CSR build ----------------
__global__ void count_seg(const int* __restrict__ ei, const int* __restrict__ et,
                          int* __restrict__ segc)
{
    int e = blockIdx.x * blockDim.x + threadIdx.x;
    if (e < EE) {
        int dst = ei[EE + e];
        int r = et[e];
        atomicAdd(&segc[r * NN + dst], 1);
    }
}

__global__ __launch_bounds__(256) void scan_local(const int* __restrict__ segc,
                                                  int* __restrict__ offs,
                                                  int* __restrict__ bsum)
{
    int b = blockIdx.x;
    int base = b * CHUNK;
    int tid = threadIdx.x;
    int lane = tid & 63, wave = tid >> 6;
    __shared__ int wsum[4];
    int vals[8];
    int i0 = base + tid * 8;
    int s = 0;
    if (i0 + 7 < NSEG) {
        int4 v0 = *(const int4*)&segc[i0];
        int4 v1 = *(const int4*)&segc[i0 + 4];
        vals[0] = v0.x; vals[1] = v0.y; vals[2] = v0.z; vals[3] = v0.w;
        vals[4] = v1.x; vals[5] = v1.y; vals[6] = v1.z; vals[7] = v1.w;
    } else {
#pragma unroll
        for (int j = 0; j < 8; j++) vals[j] = (i0 + j < NSEG) ? segc[i0 + j] : 0;
    }
#pragma unroll
    for (int j = 0; j < 8; j++) s += vals[j];
    int v = s;
#pragma unroll
    for (int off = 1; off < 64; off <<= 1) {
        int u = __shfl_up(v, off);
        if (lane >= off) v += u;
    }
    if (lane == 63) wsum[wave] = v;
    __syncthreads();
    int wbase = 0;
#pragma unroll
    for (int ww = 0; ww < 4; ww++) if (ww < wave) wbase += wsum[ww];
    int run = wbase + v - s;
#pragma unroll
    for (int j = 0; j < 8; j++) {
        run += vals[j];
        int i = i0 + j;
        if (i < NSEG) offs[i + 1] = run;
    }
    if (tid == 0) {
        int t = 0;
#pragma unroll
        for (int ww = 0; ww < 4; ww++) t += wsum[ww];
        bsum[b] = t;
    }
}

__global__ void scan_bsum(const int* __restrict__ bsum, int* __restrict__ bbase)
{
    int lane = threadIdx.x;
    int c = (lane < NB) ? bsum[lane] : 0;
    int v = c;
#pragma unroll
    for (int off = 1; off < 64; off <<= 1) {
        int u = __shfl_up(v, off);
        if (lane >= off) v += u;
    }
    if (lane < NB) bbase[lane] = v - c;
}

__global__ void add_base(int* __restrict__ offs, const int* __restrict__ bbase)
{
    int i = blockIdx.x * blockDim.x + threadIdx.x;
    if (i < NSEG) offs[i + 1] += bbase[i / CHUNK];
    if (i == 0) offs[0] = 0;
}

__global__ void fill_src(const int* __restrict__ ei, const int* __restrict__ et,
                         const int* __restrict__ offs, int* __restrict__ cursor,
                         int* __restrict__ src_list)
{
    int e = blockIdx.x * blockDim.x + threadIdx.x;
    if (e < EE) {
        int src = ei[e];
        int dst = ei[EE + e];
        int s = et[e] * NN + dst;
        int pos = offs[s] + atomicAdd(&cursor[s], 1);
        src_list[pos] = src;
    }
}

// ---------------- gather: v = base + sum_r mean(hrel_bf16) ----------------
// OUTM 0: write bf16 (next layer input).  OUTM 1: fused head -> logits.
template<int OUTM>
__global__ __launch_bounds__(256) void gather_mean_b(
    const u16* __restrict__ hrelb,
    const int* __restrict__ offs,
    const int* __restrict__ src_list,
    const float* __restrict__ basein,
    u16* __restrict__ Oh,
    const float* __restrict__ wout, const float* __restrict__ bout,
    float* __restrict__ logits)
{
    int d = blockIdx.x * 4 + (threadIdx.x >> 6);
    if (d >= NN) return;
    int lane = threadIdx.x & 63;
    f32x4 acc = {0.f, 0.f, 0.f, 0.f};
#pragma unroll
    for (int r = 0; r < 2; r++) {
        int s = r * NN + d;
        int start = offs[s], end = offs[s + 1];
        if (start == end) continue;
        f32x4 a = {0.f, 0.f, 0.f, 0.f};
        const u16* hb = hrelb + (size_t)r * NN * HD;
        for (int i = start; i < end; i++) {
            int src = src_list[i];
            uint2 wv = *(const uint2*)(hb + (size_t)src * HD + lane * 4);
            a.x += __uint_as_float(wv.x << 16);
            a.y += __uint_as_float(wv.x & 0xFFFF0000u);
            a.z += __uint_as_float(wv.y << 16);
            a.w += __uint_as_float(wv.y & 0xFFFF0000u);
        }
        float inv = 1.0f / (float)(end - start);
        acc.x += a.x * inv; acc.y += a.y * inv;
        acc.z += a.z * inv; acc.w += a.w * inv;
    }
    float4 b = ((const float4*)(basein + (size_t)d * HD))[lane];
    float v0 = b.x + acc.x, v1 = b.y + acc.y, v2 = b.z + acc.z, v3 = b.w + acc.w;
    if (OUTM == 0) {
        uint2 uh;
        uh.x = (unsigned)f2bf_rne(v0) | ((unsigned)f2bf_rne(v1) << 16);
        uh.y = (unsigned)f2bf_rne(v2) | ((unsigned)f2bf_rne(v3) << 16);
        *(uint2*)(Oh + (size_t)d * HD + lane * 4) = uh;
    } else {
        int k = lane * 4;
        float a0 = v0 * wout[(k + 0) * 2 + 0] + v1 * wout[(k + 1) * 2 + 0]
                 + v2 * wout[(k + 2) * 2 + 0] + v3 * wout[(k + 3) * 2 + 0];
        float a1 = v0 * wout[(k + 0) * 2 + 1] + v1 * wout[(k + 1) * 2 + 1]
                 + v2 * wout[(k + 2) * 2 + 1] + v3 * wout[(k + 3) * 2 + 1];
#pragma unroll
        for (int off = 32; off > 0; off >>= 1) {
            a0 += __shfl_down(a0, off);
            a1 += __shfl_down(a1, off);
        }
        if (lane == 0) {
            logits[(size_t)d * 2 + 0] = a0 + bout[0];
            logits[(size_t)d * 2 + 1] = a1 + bout[1];
        }
    }
}

extern "C" void kernel_launch(void* const* d_in, const int* in_sizes, int n_in,
                              void* d_out, int out_size, void* d_ws, size_t ws_size,
                              hipStream_t stream)
{
    const float* des   = (const float*)d_in[0];
    const float* tweet = (const float*)d_in[1];
    const float* nump  = (const float*)d_in[2];
    const float* catp  = (const float*)d_in[3];
    const int*   ei    = (const int*)d_in[4];
    const int*   et    = (const int*)d_in[5];
    const float* w_des = (const float*)d_in[6],  *b_des = (const float*)d_in[7];
    const float* w_tw  = (const float*)d_in[8],  *b_tw  = (const float*)d_in[9];
    const float* w_num = (const float*)d_in[10], *b_num = (const float*)d_in[11];
    const float* w_cat = (const float*)d_in[12], *b_cat = (const float*)d_in[13];
    const float* w_in  = (const float*)d_in[14], *b_in  = (const float*)d_in[15];
    const float* weight1 = (const float*)d_in[16], *root1 = (const float*)d_in[17], *bias1 = (const float*)d_in[18];
    const float* weight2 = (const float*)d_in[19], *root2 = (const float*)d_in[20], *bias2 = (const float*)d_in[21];
    const float* w_out = (const float*)d_in[22], *b_out = (const float*)d_in[23];
    float* outp = (float*)d_out;

    const int HSZ = HD * HD, PSZ = 768 * 64;

    // ---- workspace carve-up ----
    float* base  = (float*)d_ws;                       // [N,HD] f32
    u16*   hrelb = (u16*)(base + (size_t)NN * HD);     // [2,N,HD] bf16
    u16*   xh    = hrelb + (size_t)2 * NN * HD;        // [N,HD] bf16
    u16*   yh    = xh + (size_t)NN * HD;               // [N,HD] bf16
    int*   offs  = (int*)(yh + (size_t)NN * HD);
    int*   segc  = offs + (NSEG + 1);
    int*   srcl  = segc + NSEG;
    int*   bsum  = srcl + EE;
    int*   bbase = bsum + NB;
    uintptr_t wp = ((uintptr_t)(bbase + NB) + 15) & ~(uintptr_t)15;
    u16* desB = (u16*)wp;
    u16* twB  = desB + PSZ;
    u16* winB = twB + PSZ;
    u16* cat1 = winB + HSZ;
    u16* cat2 = cat1 + 3 * HSZ;

    // ---- CSR build ----
    hipMemsetAsync(segc, 0, NSEG * sizeof(int), stream);
    count_seg<<<(EE + 255) / 256, 256, 0, stream>>>(ei, et, segc);
    scan_local<<<NB, 256, 0, stream>>>(segc, offs, bsum);
    scan_bsum<<<1, 64, 0, stream>>>(bsum, bbase);
    add_base<<<(NSEG + 255) / 256, 256, 0, stream>>>(offs, bbase);
    hipMemsetAsync(segc, 0, NSEG * sizeof(int), stream);
    fill_src<<<(EE + 255) / 256, 256, 0, stream>>>(ei, et, offs, segc, srcl);

    // ---- weight conversion (single batched launch) ----
    const int CONV_TOT = 98304 + 7 * 65536;
    conv_all<<<(CONV_TOT + 255) / 256, 256, 0, stream>>>(
        w_des, w_tw, w_in, weight1, root1, weight2, root2,
        desB, twB, winB, cat1, cat2);

    const int NYB = (NN + 127) / 128;    // 391 (128-row blocks)
    const int NWB = (NN + 31) / 32;      // 1563 (32-row blocks = 2 waves x 16 rows)

    // ---- fused feature projections (des+tweet) -> xh ----
    gemm_projW<<<2 * NWB, 128, 0, stream>>>(des, tweet, desB, twB, b_des, b_tw, xh);
    dim3 gsm(2, (NN + 63) / 64);
    gemm_f32s2<<<gsm, 256, 0, stream>>>(nump, catp, w_num, w_cat, b_num, b_cat, xh);

    // ---- y = lrelu(x @ w_in + b_in) -> yh ----
    gemm_bf16s<1><<<2 * NYB, 256, 0, stream>>>(xh, winB, b_in, yh, nullptr, NN, 2);

    // ---- layer 1: fused [W_r0|W_r1|root1] -> hrelb (bf16) + base (f32) ----
    gemm_bf16s<2><<<6 * NYB, 256, 0, stream>>>(yh, cat1, bias1, hrelb, base, NN, 6);
    gather_mean_b<0><<<(NN + 3) / 4, 256, 0, stream>>>(hrelb, offs, srcl, base, xh, nullptr, nullptr, nullptr);

    // ---- layer 2 + fused output head ----
    gemm_bf16s<2><<<6 * NYB, 256, 0, stream>>>(xh, cat2, bias2, hrelb, base, NN, 6);
    gather_mean_b<1><<<(NN + 3) / 4, 256, 0, stream>>>(hrelb, offs, srcl, base, nullptr, w_out, b_out, outp);
}

// Round 19
// 486.279 us; speedup vs baseline: 1.1350x; 1.0891x over previous
//
#include <hip/hip_runtime.h>

#define NN 50000
#define EE 800000
#define HD 256
#define NSEG (2 * NN)
#define CHUNK 2048
#define NB ((NSEG + CHUNK - 1) / CHUNK)

typedef unsigned short u16;
typedef unsigned long long u64;
typedef short bf16x8 __attribute__((ext_vector_type(8)));
typedef float f32x4 __attribute__((ext_vector_type(4)));

__device__ __forceinline__ u16 f2bf_rne(float f) {
    unsigned u = __float_as_uint(f);
    return (u16)((u + 0x7FFF + ((u >> 16) & 1)) >> 16);
}

// bijective XCD-chunked swizzle (m204)
__device__ __forceinline__ int xcd_swizzle(int orig, int nwg) {
    int q = nwg >> 3, r = nwg & 7;
    int xcd = orig & 7, idx = orig >> 3;
    return (xcd < r ? xcd * (q + 1) : r * (q + 1) + (xcd - r) * q) + idx;
}

// async global->LDS, 16B per lane
__device__ __forceinline__ void g2l16(const void* g, void* l) {
    __builtin_amdgcn_global_load_lds(
        (const __attribute__((address_space(1))) void*)g,
        (__attribute__((address_space(3))) void*)l, 16, 0, 0);
}

// bank swizzle for 64B-row bf16 tiles
__device__ __forceinline__ int swz2(int row) { return (row & 2) | ((row >> 2) & 1); }

// stage one 128x32 bf16 tile from G[rc][K] (k-contiguous), source-swizzled
__device__ __forceinline__ void stage_bf16(const u16* __restrict__ G, u16* S,
                                           int base_rc, int maxrc, int K, int k0, int tid) {
#pragma unroll
    for (int s = 0; s < 2; s++) {
        int slot = tid + s * 256;
        int row = slot >> 2, gg = slot & 3;
        int gsrc = gg ^ swz2(row);
        int arow = base_rc + row; arow = arow < maxrc ? arow : maxrc - 1;
        g2l16(G + (size_t)arow * K + k0 + gsrc * 8, S + ((tid & ~63) + s * 256) * 8);
    }
}

// ============ counted-vmcnt dbuf bf16 GEMM body: A bf16 [M][256], B bf16 [Ncol][256] ====
// acc = A*B. BM=BN=128, 4 waves 2x2, MFMA 16x16x32, k-map k=k0+g*8+j.
// MODE 1: lrelu -> bf16 out. MODE 2: relu; col<512 -> bf16 hrel; else f32 O2.
template<int MODE>
__device__ __forceinline__ void gemm_body(
    u16* __restrict__ sA, u16* __restrict__ sB,   // each 2*4096 u16
    int bid, int nwg,
    const u16* __restrict__ Ag, const u16* __restrict__ Bg,
    const float* __restrict__ bias,
    u16* __restrict__ O1, float* __restrict__ O2,
    int M, int nxb)
{
    const int wgid = xcd_swizzle(bid, nwg);
    const int brow = (wgid / nxb) * 128, bcol = (wgid % nxb) * 128;
    const int tid = threadIdx.x, lane = tid & 63, w = tid >> 6;
    const int wr = w >> 1, wc = w & 1;
    const int r15 = lane & 15, g = lane >> 4;
    const int fsw = (g ^ swz2(r15)) * 8;

    f32x4 acc[4][4];
#pragma unroll
    for (int mi = 0; mi < 4; mi++)
#pragma unroll
        for (int ni = 0; ni < 4; ni++) acc[mi][ni] = (f32x4){0.f, 0.f, 0.f, 0.f};

    auto stage_step = [&](int k0, int b) {       // 4 VMEM instr per thread
        stage_bf16(Ag, sA + b * 4096, brow, M, 256, k0, tid);
        stage_bf16(Bg, sB + b * 4096, bcol, 1 << 30, 256, k0, tid);
    };
    auto compute_step = [&](int b) {
        bf16x8 af[4], bf[4];
#pragma unroll
        for (int mi = 0; mi < 4; mi++) {
            int idx = (wr * 64 + mi * 16 + r15) * 32 + fsw;
            af[mi] = *(const bf16x8*)&sA[b * 4096 + idx];
        }
#pragma unroll
        for (int ni = 0; ni < 4; ni++) {
            int idx = (wc * 64 + ni * 16 + r15) * 32 + fsw;
            bf[ni] = *(const bf16x8*)&sB[b * 4096 + idx];
        }
#pragma unroll
        for (int mi = 0; mi < 4; mi++)
#pragma unroll
            for (int ni = 0; ni < 4; ni++)
                acc[mi][ni] = __builtin_amdgcn_mfma_f32_16x16x32_bf16(af[mi], bf[ni], acc[mi][ni], 0, 0, 0);
    };

    stage_step(0, 0);
    stage_step(32, 1);
#pragma unroll
    for (int t = 0; t < 7; t++) {
        asm volatile("s_waitcnt vmcnt(4)" ::: "memory");   // drain buf[t&1] only
        __builtin_amdgcn_s_barrier();
        compute_step(t & 1);
        __builtin_amdgcn_s_barrier();
        if (t + 2 < 8) stage_step((t + 2) * 32, t & 1);
    }
    asm volatile("s_waitcnt vmcnt(0)" ::: "memory");
    __builtin_amdgcn_s_barrier();
    compute_step(1);

#pragma unroll
    for (int mi = 0; mi < 4; mi++) {
#pragma unroll
        for (int ni = 0; ni < 4; ni++) {
            int col = bcol + wc * 64 + ni * 16 + r15;
            float bsv = bias[col & (HD - 1)];
            int rbase = brow + wr * 64 + mi * 16 + g * 4;
#pragma unroll
            for (int r = 0; r < 4; r++) {
                int grow = rbase + r;
                if (grow >= M) continue;
                float v = acc[mi][ni][r] + bsv;
                if (MODE == 1) {
                    v = v > 0.f ? v : 0.01f * v;   // lrelu
                    O1[(size_t)grow * HD + col] = f2bf_rne(v);
                } else {
                    v = fmaxf(v, 0.f);             // relu
                    if (col < 2 * HD) {
                        O1[((size_t)(col >> 8) * NN + grow) * HD + (col & (HD - 1))] = f2bf_rne(v);
                    } else {
                        O2[(size_t)grow * HD + (col & (HD - 1))] = v;
                    }
                }
            }
        }
    }
}

// standalone layer GEMM (layer1/layer2)
template<int MODE>
__global__ __launch_bounds__(256) void gemm_bf16s(
    const u16* __restrict__ Ag, const u16* __restrict__ Bg,
    const float* __restrict__ bias,
    u16* __restrict__ O1, float* __restrict__ O2,
    int M, int nxb)
{
    __shared__ __align__(16) u16 sA[2 * 4096];
    __shared__ __align__(16) u16 sB[2 * 4096];
    gemm_body<MODE>(sA, sB, blockIdx.x, gridDim.x, Ag, Bg, bias, O1, O2, M, nxb);
}

// ===================== wave-autonomous dual-projection body (K=768) =====================
// Round-16 proven. 128-thr block = 2 independent waves; each wave 16 rows x 64 cols.
__device__ __forceinline__ void projW_body(
    u16* __restrict__ lds, int bid,
    const float* __restrict__ A0, const float* __restrict__ A1,
    const u16* __restrict__ B0, const u16* __restrict__ B1,
    const float* __restrict__ bias0, const float* __restrict__ bias1,
    u16* __restrict__ Ch)
{
    const int p = bid & 1;
    const float* __restrict__ A = p ? A1 : A0;
    const u16* __restrict__ Bp = p ? B1 : B0;
    const float* __restrict__ bias = p ? bias1 : bias0;
    const int coff = p * 64;
    const int lane = threadIdx.x & 63, w = threadIdx.x >> 6;
    const int wrow = (bid >> 1) * 32 + w * 16;
    const int r15 = lane & 15, g = lane >> 4;
    const int lbase = w * 2560;      // u16 units

    size_t aoff[2];
#pragma unroll
    for (int i = 0; i < 2; i++) {
        int row = wrow + (lane >> 3) + 8 * i;
        row = row < NN ? row : NN - 1;
        aoff[i] = (size_t)row * 768 + (lane & 7) * 4;
    }
    size_t boff[4];
#pragma unroll
    for (int ni = 0; ni < 4; ni++)
        boff[ni] = (size_t)(ni * 64 + lane) * 8;

    f32x4 acc[4];
#pragma unroll
    for (int ni = 0; ni < 4; ni++) acc[ni] = (f32x4){0.f, 0.f, 0.f, 0.f};

    float4 Ar0[2], Ar1[2];
    uint4 Bs0[4], Bs1[4];

    auto loadA = [&](int t, float4 (&d)[2]) {
#pragma unroll
        for (int i = 0; i < 2; i++) d[i] = *(const float4*)&A[aoff[i] + t * 32];
    };
    auto loadB = [&](int t, uint4 (&d)[4]) {
#pragma unroll
        for (int ni = 0; ni < 4; ni++) d[ni] = *(const uint4*)&Bp[boff[ni] + (size_t)t * 2048];
    };
    auto writeA = [&](const float4 (&s)[2], int buf) {
#pragma unroll
        for (int i = 0; i < 2; i++) {
            int row2 = (lane >> 3) + 8 * i;
            unsigned e0 = __float_as_uint(s[i].x), e1 = __float_as_uint(s[i].y),
                     e2 = __float_as_uint(s[i].z), e3 = __float_as_uint(s[i].w);
            unsigned h0 = __builtin_amdgcn_perm(e1, e0, 0x07060302u);
            unsigned h1 = __builtin_amdgcn_perm(e3, e2, 0x07060302u);
            unsigned q0 = __float_as_uint(s[i].x - __uint_as_float(e0 & 0xFFFF0000u));
            unsigned q1 = __float_as_uint(s[i].y - __uint_as_float(e1 & 0xFFFF0000u));
            unsigned q2 = __float_as_uint(s[i].z - __uint_as_float(e2 & 0xFFFF0000u));
            unsigned q3 = __float_as_uint(s[i].w - __uint_as_float(e3 & 0xFFFF0000u));
            unsigned l0 = __builtin_amdgcn_perm(q1, q0, 0x07060302u);
            unsigned l1 = __builtin_amdgcn_perm(q3, q2, 0x07060302u);
            int idx = lbase + buf * 1280 + row2 * 40 + (lane & 7) * 4;
            *(u64*)&lds[idx] = (u64)h0 | ((u64)h1 << 32);
            *(u64*)&lds[idx + 640] = (u64)l0 | ((u64)l1 << 32);
        }
    };
    auto compute = [&](int buf, const uint4 (&Bv)[4]) {
        bf16x8 afh, afl;
        {
            int idx = lbase + buf * 1280 + r15 * 40 + g * 8;
            afh = *(const bf16x8*)&lds[idx];
            afl = *(const bf16x8*)&lds[idx + 640];
        }
#pragma unroll
        for (int ni = 0; ni < 4; ni++) {
            bf16x8 bb = __builtin_bit_cast(bf16x8, Bv[ni]);
            acc[ni] = __builtin_amdgcn_mfma_f32_16x16x32_bf16(afh, bb, acc[ni], 0, 0, 0);
            acc[ni] = __builtin_amdgcn_mfma_f32_16x16x32_bf16(afl, bb, acc[ni], 0, 0, 0);
        }
    };

    // prologue (NT = 24)
    loadA(0, Ar0); loadB(0, Bs0);
    writeA(Ar0, 0);
    loadA(1, Ar1); loadB(1, Bs1);
    for (int tt = 0; tt < 11; ++tt) {
        int t0 = 2 * tt;
        loadA(t0 + 2, Ar0);
        compute(0, Bs0);
        loadB(t0 + 2, Bs0);
        writeA(Ar1, 1);
        loadA(t0 + 3, Ar1);
        compute(1, Bs1);
        loadB(t0 + 3, Bs1);
        writeA(Ar0, 0);
    }
    compute(0, Bs0);     // t=22
    writeA(Ar1, 1);      // tile 23 -> buf1
    compute(1, Bs1);     // t=23

    // ---- coalesced epilogue ----
    u16* tlh = &lds[lbase];          // 16 x 72 u16 (pad 8)
#pragma unroll
    for (int ni = 0; ni < 4; ni++) {
        int col = ni * 16 + r15;
        float bsv = bias[col];
#pragma unroll
        for (int r = 0; r < 4; r++) {
            int row = g * 4 + r;
            float v = acc[ni][r] + bsv;
            v = v > 0.f ? v : 0.01f * v;   // lrelu
            tlh[row * 72 + col] = f2bf_rne(v);
        }
    }
    asm volatile("s_waitcnt lgkmcnt(0)" ::: "memory");
    __builtin_amdgcn_sched_barrier(0);
    {
        int row = lane >> 2, cb = (lane & 3) * 16;
        int grow = wrow + row;
        if (grow < NN) {
#pragma unroll
            for (int j = 0; j < 2; j++) {
                uint4 hv = *(const uint4*)&tlh[row * 72 + cb + j * 8];
                *(uint4*)&Ch[(size_t)grow * HD + coff + cb + j * 8] = hv;
            }
        }
    }
}

// ---- small projection body (nump K=5 / catp K=3), 128 threads, 32 rows x 64 cols ----
__device__ __forceinline__ void smallproj_body(
    float* __restrict__ smem, int sbid,
    const float* __restrict__ nump, const float* __restrict__ catp,
    const float* __restrict__ w_num, const float* __restrict__ w_cat,
    const float* __restrict__ b_num, const float* __restrict__ b_cat,
    u16* __restrict__ Ch)
{
    const int NSB = (NN + 31) / 32;   // 1563
    const int p = sbid >= NSB;
    const int brow = (p ? sbid - NSB : sbid) * 32;
    const float* __restrict__ A = p ? catp : nump;
    const float* __restrict__ B = p ? w_cat : w_num;
    const float* __restrict__ bias = p ? b_cat : b_num;
    const int K = p ? 3 : 5, coff = p ? 192 : 128;
    const int tid = threadIdx.x;
    float* As = smem;          // [8][36]
    float* Bs = smem + 8 * 36; // [8][68]

#pragma unroll
    for (int s = 0; s < 2; s++) {
        int idx = tid + s * 128;
        int m = idx >> 3, k = idx & 7;
        int gr = brow + m;
        As[k * 36 + m] = (gr < NN && k < K) ? A[(size_t)gr * K + k] : 0.f;
    }
#pragma unroll
    for (int s = 0; s < 4; s++) {
        int idx = tid + s * 128;
        int k = idx >> 6, n = idx & 63;
        Bs[k * 68 + n] = (k < K) ? B[k * 64 + n] : 0.f;
    }
    __syncthreads();

    const int tx = tid & 15, ty = tid >> 4;
    float acc[4][4];
#pragma unroll
    for (int i = 0; i < 4; i++)
#pragma unroll
        for (int j = 0; j < 4; j++) acc[i][j] = 0.f;
#pragma unroll
    for (int k = 0; k < 8; k++) {
        float a[4], b[4];
#pragma unroll
        for (int i = 0; i < 4; i++) a[i] = As[k * 36 + ty * 4 + i];
#pragma unroll
        for (int j = 0; j < 4; j++) b[j] = Bs[k * 68 + tx * 4 + j];
#pragma unroll
        for (int i = 0; i < 4; i++)
#pragma unroll
            for (int j = 0; j < 4; j++) acc[i][j] = fmaf(a[i], b[j], acc[i][j]);
    }
#pragma unroll
    for (int i = 0; i < 4; i++) {
        int gr = brow + ty * 4 + i;
        if (gr >= NN) continue;
#pragma unroll
        for (int j = 0; j < 4; j++) {
            int gc = tx * 4 + j;
            float v = acc[i][j] + bias[gc];
            v = v > 0.f ? v : 0.01f * v;
            Ch[(size_t)gr * HD + coff + gc] = f2bf_rne(v);
        }
    }
}

// ==== MEGA-KERNEL 1 (128 threads): projW | smallproj | count_seg | conv_hd ====
__global__ __launch_bounds__(128) void mega1(
    const float* __restrict__ des, const float* __restrict__ tweet,
    const u16* __restrict__ desB, const u16* __restrict__ twB,
    const float* __restrict__ b_des, const float* __restrict__ b_tw,
    u16* __restrict__ xh,
    const float* __restrict__ nump, const float* __restrict__ catp,
    const float* __restrict__ w_num, const float* __restrict__ w_cat,
    const float* __restrict__ b_num, const float* __restrict__ b_cat,
    const int* __restrict__ ei, const int* __restrict__ et, int* __restrict__ segc,
    const float* __restrict__ w_in,
    const float* __restrict__ weight1, const float* __restrict__ root1,
    const float* __restrict__ weight2, const float* __restrict__ root2,
    u16* __restrict__ winB, u16* __restrict__ cat1, u16* __restrict__ cat2,
    int nproj, int nsmall, int ncount)
{
    __shared__ __align__(16) u16 smem[5120];   // 10240 B, role-reused
    int bid = blockIdx.x;
    if (bid < nproj) {
        projW_body(smem, bid, des, tweet, desB, twB, b_des, b_tw, xh);
        return;
    }
    bid -= nproj;
    if (bid < nsmall) {
        smallproj_body((float*)smem, bid, nump, catp, w_num, w_cat, b_num, b_cat, xh);
        return;
    }
    bid -= nsmall;
    if (bid < ncount) {
        int e = bid * 128 + threadIdx.x;
        if (e < EE) {
            int dst = ei[EE + e];
            int r = et[e];
            atomicAdd(&segc[r * NN + dst], 1);
        }
        return;
    }
    bid -= ncount;
    // conv_hd: 7 x 256x256 tensors -> bf16 [colOff+n][256]
    {
        const int HSZ = HD * HD;
        int idx = bid * 128 + threadIdx.x;
        int seg = idx >> 16;         // 0..6
        if (seg >= 7) return;
        int i = idx & 65535;
        const float* srcs[7] = {w_in, weight1, weight1 + HSZ, root1,
                                weight2, weight2 + HSZ, root2};
        u16* dsts[7] = {winB, cat1, cat1 + 256 * 256, cat1 + 512 * 256,
                        cat2, cat2 + 256 * 256, cat2 + 512 * 256};
        int k = i >> 8, n = i & 255;
        dsts[seg][(size_t)n * 256 + k] = f2bf_rne(srcs[seg][i]);
    }
}

// ==== MEGA-KERNEL 2 (256 threads): w_in GEMM | fill_src (atomicSub cursor) ====
__global__ __launch_bounds__(256) void mega2(
    const u16* __restrict__ xh, const u16* __restrict__ winB,
    const float* __restrict__ b_in, u16* __restrict__ yh,
    const int* __restrict__ ei, const int* __restrict__ et,
    const int* __restrict__ offs, int* __restrict__ cursor,
    int* __restrict__ src_list,
    int nwin)
{
    __shared__ __align__(16) u16 sA[2 * 4096];
    __shared__ __align__(16) u16 sB[2 * 4096];
    int bid = blockIdx.x;
    if (bid < nwin) {
        gemm_body<1>(sA, sB, bid, nwin, xh, winB, b_in, yh, nullptr, NN, 2);
        return;
    }
    int e = (bid - nwin) * 256 + threadIdx.x;
    if (e < EE) {
        int src = ei[e];
        int dst = ei[EE + e];
        int s = et[e] * NN + dst;
        int old = atomicSub(&cursor[s], 1);       // counts -> cursor, no extra memset
        src_list[offs[s] + old - 1] = src;
    }
}

// ---- projection weights -> fragment-major (must precede mega1) ----
__global__ void conv_proj(const float* __restrict__ w_des, const float* __restrict__ w_tw,
                          u16* __restrict__ desB, u16* __restrict__ twB)
{
    int idx = blockIdx.x * 256 + threadIdx.x;
    if (idx >= 98304) return;
    const float* W = idx < 49152 ? w_des : w_tw;
    u16* Bf = idx < 49152 ? desB : twB;
    int i = idx < 49152 ? idx : idx - 49152;
    int k = i >> 6, n = i & 63;
    int t = k >> 5, kk = k & 31, g = kk >> 3, j = kk & 7;
    int lane = g * 16 + (n & 15), ni = n >> 4;
    Bf[(size_t)((t * 4 + ni) * 64 + lane) * 8 + j] = f2bf_rne(W[i]);
}

// ---------------- CSR scan chain ----------------
__global__ __launch_bounds__(256) void scan_local(const int* __restrict__ segc,
                                                  int* __restrict__ offs,
                                                  int* __restrict__ bsum)
{
    int b = blockIdx.x;
    int base = b * CHUNK;
    int tid = threadIdx.x;
    int lane = tid & 63, wave = tid >> 6;
    __shared__ int wsum[4];
    int vals[8];
    int i0 = base + tid * 8;
    int s = 0;
    if (i0 + 7 < NSEG) {
        int4 v0 = *(const int4*)&segc[i0];
        int4 v1 = *(const int4*)&segc[i0 + 4];
        vals[0] = v0.x; vals[1] = v0.y; vals[2] = v0.z; vals[3] = v0.w;
        vals[4] = v1.x; vals[5] = v1.y; vals[6] = v1.z; vals[7] = v1.w;
    } else {
#pragma unroll
        for (int j = 0; j < 8; j++) vals[j] = (i0 + j < NSEG) ? segc[i0 + j] : 0;
    }
#pragma unroll
    for (int j = 0; j < 8; j++) s += vals[j];
    int v = s;
#pragma unroll
    for (int off = 1; off < 64; off <<= 1) {
        int u = __shfl_up(v, off);
        if (lane >= off) v += u;
    }
    if (lane == 63) wsum[wave] = v;
    __syncthreads();
    int wbase = 0;
#pragma unroll
    for (int ww = 0; ww < 4; ww++) if (ww < wave) wbase += wsum[ww];
    int run = wbase + v - s;
#pragma unroll
    for (int j = 0; j < 8; j++) {
        run += vals[j];
        int i = i0 + j;
        if (i < NSEG) offs[i + 1] = run;
    }
    if (tid == 0) {
        int t = 0;
#pragma unroll
        for (int ww = 0; ww < 4; ww++) t += wsum[ww];
        bsum[b] = t;
    }
}

__global__ void scan_bsum(const int* __restrict__ bsum, int* __restrict__ bbase)
{
    int lane = threadIdx.x;
    int c = (lane < NB) ? bsum[lane] : 0;
    int v = c;
#pragma unroll
    for (int off = 1; off < 64; off <<= 1) {
        int u = __shfl_up(v, off);
        if (lane >= off) v += u;
    }
    if (lane < NB) bbase[lane] = v - c;
}

__global__ void add_base(int* __restrict__ offs, const int* __restrict__ bbase)
{
    int i = blockIdx.x * blockDim.x + threadIdx.x;
    if (i < NSEG) offs[i + 1] += bbase[i / CHUNK];
    if (i == 0) offs[0] = 0;
}

// ---------------- gather: v = base + sum_r mean(hrel_bf16) ----------------
// OUTM 0: write bf16 (next layer input).  OUTM 1: fused head -> logits.
template<int OUTM>
__global__ __launch_bounds__(256) void gather_mean_b(
    const u16* __restrict__ hrelb,
    const int* __restrict__ offs,
    const int* __restrict__ src_list,
    const float* __restrict__ basein,
    u16* __restrict__ Oh,
    const float* __restrict__ wout, const float* __restrict__ bout,
    float* __restrict__ logits)
{
    int d = blockIdx.x * 4 + (threadIdx.x >> 6);
    if (d >= NN) return;
    int lane = threadIdx.x & 63;
    f32x4 acc = {0.f, 0.f, 0.f, 0.f};
#pragma unroll
    for (int r = 0; r < 2; r++) {
        int s = r * NN + d;
        int start = offs[s], end = offs[s + 1];
        if (start == end) continue;
        f32x4 a = {0.f, 0.f, 0.f, 0.f};
        const u16* hb = hrelb + (size_t)r * NN * HD;
        for (int i = start; i < end; i++) {
            int src = src_list[i];
            uint2 wv = *(const uint2*)(hb + (size_t)src * HD + lane * 4);
            a.x += __uint_as_float(wv.x << 16);
            a.y += __uint_as_float(wv.x & 0xFFFF0000u);
            a.z += __uint_as_float(wv.y << 16);
            a.w += __uint_as_float(wv.y & 0xFFFF0000u);
        }
        float inv = 1.0f / (float)(end - start);
        acc.x += a.x * inv; acc.y += a.y * inv;
        acc.z += a.z * inv; acc.w += a.w * inv;
    }
    float4 b = ((const float4*)(basein + (size_t)d * HD))[lane];
    float v0 = b.x + acc.x, v1 = b.y + acc.y, v2 = b.z + acc.z, v3 = b.w + acc.w;
    if (OUTM == 0) {
        uint2 uh;
        uh.x = (unsigned)f2bf_rne(v0) | ((unsigned)f2bf_rne(v1) << 16);
        uh.y = (unsigned)f2bf_rne(v2) | ((unsigned)f2bf_rne(v3) << 16);
        *(uint2*)(Oh + (size_t)d * HD + lane * 4) = uh;
    } else {
        int k = lane * 4;
        float a0 = v0 * wout[(k + 0) * 2 + 0] + v1 * wout[(k + 1) * 2 + 0]
                 + v2 * wout[(k + 2) * 2 + 0] + v3 * wout[(k + 3) * 2 + 0];
        float a1 = v0 * wout[(k + 0) * 2 + 1] + v1 * wout[(k + 1) * 2 + 1]
                 + v2 * wout[(k + 2) * 2 + 1] + v3 * wout[(k + 3) * 2 + 1];
#pragma unroll
        for (int off = 32; off > 0; off >>= 1) {
            a0 += __shfl_down(a0, off);
            a1 += __shfl_down(a1, off);
        }
        if (lane == 0) {
            logits[(size_t)d * 2 + 0] = a0 + bout[0];
            logits[(size_t)d * 2 + 1] = a1 + bout[1];
        }
    }
}

extern "C" void kernel_launch(void* const* d_in, const int* in_sizes, int n_in,
                              void* d_out, int out_size, void* d_ws, size_t ws_size,
                              hipStream_t stream)
{
    const float* des   = (const float*)d_in[0];
    const float* tweet = (const float*)d_in[1];
    const float* nump  = (const float*)d_in[2];
    const float* catp  = (const float*)d_in[3];
    const int*   ei    = (const int*)d_in[4];
    const int*   et    = (const int*)d_in[5];
    const float* w_des = (const float*)d_in[6],  *b_des = (const float*)d_in[7];
    const float* w_tw  = (const float*)d_in[8],  *b_tw  = (const float*)d_in[9];
    const float* w_num = (const float*)d_in[10], *b_num = (const float*)d_in[11];
    const float* w_cat = (const float*)d_in[12], *b_cat = (const float*)d_in[13];
    const float* w_in  = (const float*)d_in[14], *b_in  = (const float*)d_in[15];
    const float* weight1 = (const float*)d_in[16], *root1 = (const float*)d_in[17], *bias1 = (const float*)d_in[18];
    const float* weight2 = (const float*)d_in[19], *root2 = (const float*)d_in[20], *bias2 = (const float*)d_in[21];
    const float* w_out = (const float*)d_in[22], *b_out = (const float*)d_in[23];
    float* outp = (float*)d_out;

    const int HSZ = HD * HD, PSZ = 768 * 64;

    // ---- workspace carve-up ----
    float* base  = (float*)d_ws;                       // [N,HD] f32
    u16*   hrelb = (u16*)(base + (size_t)NN * HD);     // [2,N,HD] bf16
    u16*   xh    = hrelb + (size_t)2 * NN * HD;        // [N,HD] bf16
    u16*   yh    = xh + (size_t)NN * HD;               // [N,HD] bf16
    int*   offs  = (int*)(yh + (size_t)NN * HD);
    int*   segc  = offs + (NSEG + 1);
    int*   srcl  = segc + NSEG;
    int*   bsum  = srcl + EE;
    int*   bbase = bsum + NB;
    uintptr_t wp = ((uintptr_t)(bbase + NB) + 15) & ~(uintptr_t)15;
    u16* desB = (u16*)wp;
    u16* twB  = desB + PSZ;
    u16* winB = twB + PSZ;
    u16* cat1 = winB + HSZ;
    u16* cat2 = cat1 + 3 * HSZ;

    const int NYB = (NN + 127) / 128;    // 391 (128-row blocks)
    const int NWB = (NN + 31) / 32;      // 1563 (32-row blocks = 2 waves x 16 rows)
    const int NSB = (NN + 31) / 32;      // 1563 (smallproj 32-row blocks)

    // 1. zero segment counters
    hipMemsetAsync(segc, 0, NSEG * sizeof(int), stream);
    // 2. projection weights -> fragment-major (needed by mega1's projW)
    conv_proj<<<(98304 + 255) / 256, 256, 0, stream>>>(w_des, w_tw, desB, twB);
    // 3. MEGA1: projW + smallproj + count_seg + conv_hd
    const int nproj = 2 * NWB;                    // 3126
    const int nsmall = 2 * NSB;                   // 3126
    const int ncount = (EE + 127) / 128;          // 6250
    const int nconv = (7 * 65536 + 127) / 128;    // 3584
    mega1<<<nproj + nsmall + ncount + nconv, 128, 0, stream>>>(
        des, tweet, desB, twB, b_des, b_tw, xh,
        nump, catp, w_num, w_cat, b_num, b_cat,
        ei, et, segc,
        w_in, weight1, root1, weight2, root2,
        winB, cat1, cat2,
        nproj, nsmall, ncount);
    // 4-6. scan chain
    scan_local<<<NB, 256, 0, stream>>>(segc, offs, bsum);
    scan_bsum<<<1, 64, 0, stream>>>(bsum, bbase);
    add_base<<<(NSEG + 255) / 256, 256, 0, stream>>>(offs, bbase);
    // 7. MEGA2: w_in GEMM + fill_src (atomicSub on counts)
    const int nwin = 2 * NYB;                     // 782
    const int nfill = (EE + 255) / 256;           // 3125
    mega2<<<nwin + nfill, 256, 0, stream>>>(xh, winB, b_in, yh,
                                            ei, et, offs, segc, srcl, nwin);
    // 8-9. layer 1
    gemm_bf16s<2><<<6 * NYB, 256, 0, stream>>>(yh, cat1, bias1, hrelb, base, NN, 6);
    gather_mean_b<0><<<(NN + 3) / 4, 256, 0, stream>>>(hrelb, offs, srcl, base, xh, nullptr, nullptr, nullptr);
    // 10-11. layer 2 + fused output head
    gemm_bf16s<2><<<6 * NYB, 256, 0, stream>>>(xh, cat2, bias2, hrelb, base, NN, 6);
    gather_mean_b<1><<<(NN + 3) / 4, 256, 0, stream>>>(hrelb, offs, srcl, base, nullptr, w_out, b_out, outp);
}